// Round 3
// baseline (777.705 us; speedup 1.0000x reference)
//
#include <hip/hip_runtime.h>
#include <math.h>

#define MUL 32
#define NATTR 4
#define NBASIS 10
#define HID 64
#define OUT_DIM 16
#define NGRAPH 8

#define PI_F 3.14159265358979323846f
#define SQRT3_F 1.7320508075688772f
#define INV_SQRT3_F 0.5773502691896258f
#define INV_SQRT10_F 0.31622776601683794f
#define INV_SQRTNN_F 0.17677669529663687f   // 1/sqrt(32)
#define NORM128_F 0.08838834764831845f      // 1/sqrt(128)
#define NORM256_F 0.0625f                   // 1/sqrt(256)
#define C_S_F 0.3826834323650898f           // sin(pi/8)
#define C_X_F 0.9238795325112867f           // cos(pi/8)
#define CSTEP_F (4.0f/9.0f)                 // linspace(0,4,10) step

// ---------------------------------------------------------------- init s,v
__global__ void init_sv(const float* __restrict__ x,
                        float* __restrict__ s, float* __restrict__ v, int N) {
    int i = blockIdx.x * 256 + threadIdx.x;
    if (i >= N * 128) return;
    int n = i >> 7, c = i & 127;
    float val = x[i];
    if (c < 32) s[n * 32 + c] = val;
    else        v[n * 96 + (c - 32)] = val;
}

// ---------------------------------------------------------------- CSR build
__global__ void csr_count(const int* __restrict__ edst, int* __restrict__ cnt, int E) {
    int e = blockIdx.x * 256 + threadIdx.x;
    if (e < E) atomicAdd(&cnt[edst[e]], 1);
}

__global__ void csr_scan(const int* __restrict__ cnt, int* __restrict__ off,
                         int* __restrict__ cursor, int N) {
    __shared__ int sums[256];
    int t = threadIdx.x;
    int chunk = (N + 255) / 256;
    int lo = t * chunk, hi = lo + chunk; if (hi > N) hi = N;
    int s = 0;
    for (int i = lo; i < hi; i++) s += cnt[i];
    sums[t] = s;
    __syncthreads();
    for (int d = 1; d < 256; d <<= 1) {
        int v = (t >= d) ? sums[t - d] : 0;
        __syncthreads();
        sums[t] += v;
        __syncthreads();
    }
    int run = (t == 0) ? 0 : sums[t - 1];
    for (int i = lo; i < hi; i++) {
        off[i] = run; cursor[i] = run;
        run += cnt[i];
    }
}

__global__ void csr_fill(const int* __restrict__ edst, int* __restrict__ cursor,
                         int* __restrict__ eid, int E) {
    int e = blockIdx.x * 256 + threadIdx.x;
    if (e < E) { int p = atomicAdd(&cursor[edst[e]], 1); eid[p] = e; }
}

// ------------------------------------------- node fctp, scalar path (s -> 2 outputs)
// 32 nodes/block (4 sub-batches of 8) to amortize the 32KB weight load.
__global__ __launch_bounds__(256, 2) void node_s_fctp(
    const float* __restrict__ s, const float* __restrict__ attr,
    const float* __restrict__ W0, const float* __restrict__ W1,
    float* __restrict__ out0, float* __restrict__ out1, int N) {
    __shared__ float w0[4096], w1[4096];
    __shared__ float sh_s[8][32];
    int ln = threadIdx.x >> 5, w = threadIdx.x & 31;
    for (int i = threadIdx.x; i < 4096; i += 256) { w0[i] = W0[i]; w1[i] = W1[i]; }
    for (int g = 0; g < 4; g++) {
        int n = blockIdx.x * 32 + g * 8 + ln;
        bool valid = n < N;
        __syncthreads();
        if (valid) sh_s[ln][w] = s[n * 32 + w];
        __syncthreads();
        if (!valid) continue;
        float4 at = *(const float4*)(attr + n * 4);
        float fa[4] = {at.x, at.y, at.z, at.w};
        float acc0 = 0.f, acc1 = 0.f;
        for (int u = 0; u < 32; u++) {
            float su = sh_s[ln][u];
            int base = u * 128 + w;
#pragma unroll
            for (int a = 0; a < 4; a++) {
                float c = su * fa[a];
                acc0 += c * w0[base + a * 32];
                acc1 += c * w1[base + a * 32];
            }
        }
        out0[n * 32 + w] = acc0 * NORM128_F;
        out1[n * 32 + w] = acc1 * NORM128_F;
    }
}

// ------------------------------------------- node fctp, vector path (v -> 2 outputs)
__global__ __launch_bounds__(256, 2) void node_v_fctp(
    const float* __restrict__ v, const float* __restrict__ attr,
    const float* __restrict__ W0, const float* __restrict__ W1,
    float* __restrict__ out0, float* __restrict__ out1, int N) {
    __shared__ float w0[4096], w1[4096];
    __shared__ float sh_v[8][96];
    int ln = threadIdx.x >> 5, w = threadIdx.x & 31;
    for (int i = threadIdx.x; i < 4096; i += 256) { w0[i] = W0[i]; w1[i] = W1[i]; }
    for (int g = 0; g < 4; g++) {
        int n = blockIdx.x * 32 + g * 8 + ln;
        bool valid = n < N;
        __syncthreads();
        if (valid) {
            sh_v[ln][w * 3 + 0] = v[n * 96 + w * 3 + 0];
            sh_v[ln][w * 3 + 1] = v[n * 96 + w * 3 + 1];
            sh_v[ln][w * 3 + 2] = v[n * 96 + w * 3 + 2];
        }
        __syncthreads();
        if (!valid) continue;
        float4 at = *(const float4*)(attr + n * 4);
        float fa[4] = {at.x, at.y, at.z, at.w};
        float a00 = 0, a01 = 0, a02 = 0, a10 = 0, a11 = 0, a12 = 0;
        for (int u = 0; u < 32; u++) {
            float vu0 = sh_v[ln][u * 3 + 0];
            float vu1 = sh_v[ln][u * 3 + 1];
            float vu2 = sh_v[ln][u * 3 + 2];
            int base = u * 128 + w;
#pragma unroll
            for (int a = 0; a < 4; a++) {
                float f = fa[a];
                float c0 = vu0 * f, c1 = vu1 * f, c2 = vu2 * f;
                float W0v = w0[base + a * 32], W1v = w1[base + a * 32];
                a00 += c0 * W0v; a01 += c1 * W0v; a02 += c2 * W0v;
                a10 += c0 * W1v; a11 += c1 * W1v; a12 += c2 * W1v;
            }
        }
        out0[n * 96 + w * 3 + 0] = a00 * NORM128_F;
        out0[n * 96 + w * 3 + 1] = a01 * NORM128_F;
        out0[n * 96 + w * 3 + 2] = a02 * NORM128_F;
        out1[n * 96 + w * 3 + 0] = a10 * NORM128_F;
        out1[n * 96 + w * 3 + 1] = a11 * NORM128_F;
        out1[n * 96 + w * 3 + 2] = a12 * NORM128_F;
    }
}

// ---------------------------------------------------------------- edge weights
// 64 edges/block: emb -> h (silu) -> w. w staged through LDS in two 32-edge
// halves so the global store is a coalesced float4 sweep.
__global__ __launch_bounds__(256, 4) void edge_weights(
    const float* __restrict__ edge_vec,
    const float* __restrict__ Wfc1, const float* __restrict__ Wfc2,
    float* __restrict__ w_buf, float* __restrict__ y_buf, int E) {
    __shared__ float sh_wfc1[NBASIS * 64];   // [j][k]
    __shared__ float sh_embT[NBASIS * 64];   // [j][e]
    __shared__ float sh_h[64 * 65];          // [e][k], stride 65
    __shared__ float sh_w[32 * 132];         // [e_half][u*4+c], stride 132

    int tid = threadIdx.x;
    int e0 = blockIdx.x * 64;

    for (int i = tid; i < 640; i += 256) sh_wfc1[i] = Wfc1[i];
    if (tid < 64) {
        int e = e0 + tid;
        float ex = 0.f, ey = 0.f, ez = 0.f;
        if (e < E) {
            ex = edge_vec[e * 3 + 0]; ey = edge_vec[e * 3 + 1]; ez = edge_vec[e * 3 + 2];
        }
        float len = sqrtf(ex * ex + ey * ey + ez * ez);
        float rinv = SQRT3_F / (len + 1e-9f);
        if (e < E) {
            float4 y4 = {ex * rinv, ey * rinv, ez * rinv, len};
            *(float4*)(y_buf + (size_t)e * 4) = y4;
        }
        float uu = 2.0f * (len * 0.25f - 1.0f);
        float cut = (uu > 0.0f) ? 0.0f
                  : ((uu < -1.0f) ? 1.0f : 0.5f * (1.0f - __cosf(PI_F * uu)));
#pragma unroll
        for (int j = 0; j < NBASIS; j++) {
            float d = (len - j * CSTEP_F) * 2.5f;
            sh_embT[j * 64 + tid] = __expf(-d * d) * cut;
        }
    }
    __syncthreads();

    // ---- phase 1: h[e][k] = silu((emb @ Wfc1)/sqrt(10))
    {
        int k = tid & 63;
        int eb = (tid >> 6) * 16;
        float acc[16];
#pragma unroll
        for (int i = 0; i < 16; i++) acc[i] = 0.f;
#pragma unroll
        for (int j = 0; j < NBASIS; j++) {
            float wv = sh_wfc1[j * 64 + k];
#pragma unroll
            for (int i = 0; i < 16; i++) acc[i] += wv * sh_embT[j * 64 + eb + i];
        }
#pragma unroll
        for (int i = 0; i < 16; i++) {
            float a = acc[i] * INV_SQRT10_F;
            sh_h[(eb + i) * 65 + k] = a / (1.0f + __expf(-a));
        }
    }
    __syncthreads();

    // ---- phase 2: w[e][c] = (h @ Wfc2)/8, two 32-edge halves through LDS.
    // thread tile: 2 edges x 8 outputs. Output channel wq = wt*8+j maps to
    // transposed slot u = wq&31, c = wq>>5 : sh_w[e][u*4+c].
    int wt = tid & 15;   // outputs wt*8 .. wt*8+7
    int et = tid >> 4;   // edge pair et*2, et*2+1 within the half
    const float* W2 = Wfc2 + wt * 8;
    int c = wt >> 2;
    int u0 = (wt & 3) * 8;
    for (int half = 0; half < 2; half++) {
        float acc[2][8];
#pragma unroll
        for (int ie = 0; ie < 2; ie++)
#pragma unroll
            for (int j = 0; j < 8; j++) acc[ie][j] = 0.f;
        int ebase = half * 32 + et * 2;
#pragma unroll 4
        for (int k = 0; k < HID; k++) {
            float4 b0 = *(const float4*)(W2 + k * 128);
            float4 b1 = *(const float4*)(W2 + k * 128 + 4);
            float bv[8] = {b0.x, b0.y, b0.z, b0.w, b1.x, b1.y, b1.z, b1.w};
            float hv0 = sh_h[ebase * 65 + k];
            float hv1 = sh_h[(ebase + 1) * 65 + k];
#pragma unroll
            for (int j = 0; j < 8; j++) {
                acc[0][j] += hv0 * bv[j];
                acc[1][j] += hv1 * bv[j];
            }
        }
#pragma unroll
        for (int ie = 0; ie < 2; ie++) {
            float* dst = sh_w + (et * 2 + ie) * 132 + c;
#pragma unroll
            for (int j = 0; j < 8; j++) dst[(u0 + j) * 4] = acc[ie][j] * 0.125f;
        }
        __syncthreads();
        // coalesced sweep: 32 edges x 32 float4
        int base_e = e0 + half * 32;
        for (int i = tid; i < 1024; i += 256) {
            int el = i >> 5, col = i & 31;
            int e = base_e + el;
            if (e < E) {
                float4 val = *(const float4*)(sh_w + el * 132 + col * 4);
                *(float4*)(w_buf + (size_t)e * 128 + col * 4) = val;
            }
        }
        __syncthreads();
    }
}

// ---------------------------------------------------------------- gather
// one wave per dst node; half-wave per edge; lane u = channel u (0..31).
__global__ __launch_bounds__(256, 4) void gather_msgs(
    const int* __restrict__ off, const int* __restrict__ cnt,
    const int* __restrict__ eid, const int* __restrict__ esrc,
    const float* __restrict__ w_buf, const float* __restrict__ y_buf,
    const float* __restrict__ xs, const float* __restrict__ xv,
    float* __restrict__ agg_s, float* __restrict__ agg_v, int N) {
    int node = blockIdx.x * 4 + (threadIdx.x >> 6);
    if (node >= N) return;
    int lane = threadIdx.x & 63;
    int half = lane >> 5;
    int u = lane & 31;
    int o = off[node], deg = cnt[node];
    float as0 = 0, as1 = 0;
    float av00 = 0, av01 = 0, av02 = 0, av10 = 0, av11 = 0, av12 = 0;
    for (int i = half; i < deg; i += 2) {
        int e = eid[o + i];
        int src = esrc[e];
        float4 wv = *(const float4*)(w_buf + (size_t)e * 128 + u * 4);
        float4 y  = *(const float4*)(y_buf + (size_t)e * 4);
        float sE = xs[src * 32 + u];
        const float* vp = xv + src * 96 + u * 3;
        float v0 = vp[0], v1 = vp[1], v2 = vp[2];
        as0 += wv.x * sE;
        as1 += wv.y * (y.x * v0 + y.y * v1 + y.z * v2) * INV_SQRT3_F;
        float t = wv.z * sE;
        av00 += t * y.x;  av01 += t * y.y;  av02 += t * y.z;
        av10 += wv.w * v0; av11 += wv.w * v1; av12 += wv.w * v2;
    }
    as0 += __shfl_down(as0, 32);  as1 += __shfl_down(as1, 32);
    av00 += __shfl_down(av00, 32); av01 += __shfl_down(av01, 32); av02 += __shfl_down(av02, 32);
    av10 += __shfl_down(av10, 32); av11 += __shfl_down(av11, 32); av12 += __shfl_down(av12, 32);
    if (half == 0) {
        agg_s[node * 64 + u]      = as0 * INV_SQRTNN_F;
        agg_s[node * 64 + 32 + u] = as1 * INV_SQRTNN_F;
        float* av = agg_v + (size_t)node * 192;
        av[u * 3 + 0]      = av00 * INV_SQRTNN_F;
        av[u * 3 + 1]      = av01 * INV_SQRTNN_F;
        av[u * 3 + 2]      = av02 * INV_SQRTNN_F;
        av[96 + u * 3 + 0] = av10 * INV_SQRTNN_F;
        av[96 + u * 3 + 1] = av11 * INV_SQRTNN_F;
        av[96 + u * 3 + 2] = av12 * INV_SQRTNN_F;
    }
}

// ------------------------------------------- second fctp (64-wide) + s update
__global__ __launch_bounds__(256, 2) void node_update_s(
    const float* __restrict__ agg_s, const float* __restrict__ attr,
    const float* __restrict__ W0, const float* __restrict__ sc_s,
    float* __restrict__ s, float* __restrict__ snew, int N) {
    __shared__ float w0[8192];
    __shared__ float sh_as[8][64];
    int ln = threadIdx.x >> 5, w = threadIdx.x & 31;
    for (int i = threadIdx.x; i < 8192; i += 256) w0[i] = W0[i];
    for (int g = 0; g < 4; g++) {
        int n = blockIdx.x * 32 + g * 8 + ln;
        bool valid = n < N;
        __syncthreads();
        if (valid) {
            sh_as[ln][w] = agg_s[n * 64 + w];
            sh_as[ln][32 + w] = agg_s[n * 64 + 32 + w];
        }
        __syncthreads();
        if (!valid) continue;
        float4 at = *(const float4*)(attr + n * 4);
        float fa[4] = {at.x, at.y, at.z, at.w};
        float acc = 0.f;
        for (int u = 0; u < 64; u++) {
            float g_ = sh_as[ln][u];
            int base = u * 128 + w;
#pragma unroll
            for (int a = 0; a < 4; a++) acc += g_ * fa[a] * w0[base + a * 32];
        }
        float os = acc * NORM256_F;
        float sn = C_S_F * sc_s[n * 32 + w] + C_X_F * os;
        snew[n * 32 + w] = sn;
        float sig = 1.0f / (1.0f + __expf(-sn));
        s[n * 32 + w] += sn * sig;   // silu(sn)
    }
}

// ------------------------------------------- second fctp (64-wide) + v update
__global__ __launch_bounds__(256, 2) void node_update_v(
    const float* __restrict__ agg_v, const float* __restrict__ attr,
    const float* __restrict__ W1, const float* __restrict__ sc_v,
    const float* __restrict__ snew, float* __restrict__ v, int N) {
    __shared__ float w1[8192];
    __shared__ float sh_av[8][192];
    int ln = threadIdx.x >> 5, w = threadIdx.x & 31;
    for (int i = threadIdx.x; i < 8192; i += 256) w1[i] = W1[i];
    for (int g = 0; g < 4; g++) {
        int n = blockIdx.x * 32 + g * 8 + ln;
        bool valid = n < N;
        __syncthreads();
        if (valid) {
#pragma unroll
            for (int i = 0; i < 6; i++)
                sh_av[ln][w * 6 + i] = agg_v[(size_t)n * 192 + w * 6 + i];
        }
        __syncthreads();
        if (!valid) continue;
        float4 at = *(const float4*)(attr + n * 4);
        float fa[4] = {at.x, at.y, at.z, at.w};
        float a0 = 0.f, a1 = 0.f, a2 = 0.f;
        for (int u = 0; u < 64; u++) {
            float g0 = sh_av[ln][u * 3 + 0];
            float g1 = sh_av[ln][u * 3 + 1];
            float g2 = sh_av[ln][u * 3 + 2];
            int base = u * 128 + w;
#pragma unroll
            for (int a = 0; a < 4; a++) {
                float f = fa[a];
                float W1v = w1[base + a * 32];
                a0 += g0 * f * W1v; a1 += g1 * f * W1v; a2 += g2 * f * W1v;
            }
        }
        float sn = snew[n * 32 + w];
        float sig = 1.0f / (1.0f + __expf(-sn));
        float ov0 = a0 * NORM256_F, ov1 = a1 * NORM256_F, ov2 = a2 * NORM256_F;
        v[n * 96 + w * 3 + 0] += (C_S_F * sc_v[n * 96 + w * 3 + 0] + C_X_F * ov0) * sig;
        v[n * 96 + w * 3 + 1] += (C_S_F * sc_v[n * 96 + w * 3 + 1] + C_X_F * ov1) * sig;
        v[n * 96 + w * 3 + 2] += (C_S_F * sc_v[n * 96 + w * 3 + 2] + C_X_F * ov2) * sig;
    }
}

// ---------------------------------------------------------------- readout
// 64 nodes/block; per-block LDS reduction kills the 128-address atomic storm.
__global__ __launch_bounds__(256) void readout(
    const float* __restrict__ s, const float* __restrict__ attr,
    const float* __restrict__ Wread, const int* __restrict__ batch,
    float* __restrict__ out, int N, float pool_scale) {
    __shared__ float wr[2048];
    __shared__ float red[NGRAPH * 16];
    for (int i = threadIdx.x; i < 2048; i += 256) wr[i] = Wread[i];
    if (threadIdx.x < NGRAPH * 16) red[threadIdx.x] = 0.f;
    __syncthreads();
    int ln = threadIdx.x >> 4, w = threadIdx.x & 15;
    for (int g = 0; g < 4; g++) {
        int n = blockIdx.x * 64 + g * 16 + ln;
        if (n < N) {
            float4 at = *(const float4*)(attr + n * 4);
            float fa[4] = {at.x, at.y, at.z, at.w};
            float acc = 0.f;
            for (int u = 0; u < 32; u++) {
                float su = s[n * 32 + u];
                int base = u * 64 + w;
#pragma unroll
                for (int a = 0; a < 4; a++) acc += su * fa[a] * wr[base + a * 16];
            }
            atomicAdd(&red[batch[n] * 16 + w], acc);
        }
    }
    __syncthreads();
    if (threadIdx.x < NGRAPH * 16) {
        float val = red[threadIdx.x];
        if (val != 0.f)
            atomicAdd(&out[threadIdx.x], val * NORM128_F * pool_scale);
    }
}

// ---------------------------------------------------------------- launch
extern "C" void kernel_launch(void* const* d_in, const int* in_sizes, int n_in,
                              void* d_out, int out_size, void* d_ws, size_t ws_size,
                              hipStream_t stream) {
    const float* x        = (const float*)d_in[0];
    const float* nattr    = (const float*)d_in[1];
    const float* edge_vec = (const float*)d_in[2];
    const int*   batch    = (const int*)d_in[3];
    const int*   esrc     = (const int*)d_in[4];
    const int*   edst     = (const int*)d_in[5];
    const float* Wsc0  = (const float*)d_in[6];
    const float* Wsc1  = (const float*)d_in[7];
    const float* Wl10  = (const float*)d_in[8];
    const float* Wl11  = (const float*)d_in[9];
    const float* Wfc1  = (const float*)d_in[10];
    const float* Wfc2  = (const float*)d_in[11];
    const float* Wl20  = (const float*)d_in[12];
    const float* Wl21  = (const float*)d_in[13];
    const float* Wread = (const float*)d_in[14];

    int N = in_sizes[0] / (MUL * 4);
    int E = in_sizes[2] / 3;

    float* p = (float*)d_ws;
    float* w_buf  = p; p += (size_t)E * 128;   // 16B-aligned float4 layout [e][u][c]
    float* y_buf  = p; p += (size_t)E * 4;
    float* s_buf  = p; p += (size_t)N * 32;
    float* v_buf  = p; p += (size_t)N * 96;
    float* sc_s   = p; p += (size_t)N * 32;
    float* sc_v   = p; p += (size_t)N * 96;
    float* xs_buf = p; p += (size_t)N * 32;
    float* xv_buf = p; p += (size_t)N * 96;
    float* snew   = p; p += (size_t)N * 32;
    float* agg_s  = p; p += (size_t)N * 64;
    float* agg_v  = p; p += (size_t)N * 192;
    int* cnt    = (int*)p; p += N;
    int* off    = (int*)p; p += N;
    int* cursor = (int*)p; p += N;
    int* eid    = (int*)p; p += E;

    init_sv<<<(N * 128 + 255) / 256, 256, 0, stream>>>(x, s_buf, v_buf, N);
    hipMemsetAsync(d_out, 0, (size_t)out_size * sizeof(float), stream);

    // CSR by destination
    hipMemsetAsync(cnt, 0, (size_t)N * sizeof(int), stream);
    csr_count<<<(E + 255) / 256, 256, 0, stream>>>(edst, cnt, E);
    csr_scan<<<1, 256, 0, stream>>>(cnt, off, cursor, N);
    csr_fill<<<(E + 255) / 256, 256, 0, stream>>>(edst, cursor, eid, E);

    for (int l = 0; l < 2; l++) {
        node_s_fctp<<<(N + 31) / 32, 256, 0, stream>>>(
            s_buf, nattr, Wsc0 + l * 4096, Wl10 + l * 4096, sc_s, xs_buf, N);
        node_v_fctp<<<(N + 31) / 32, 256, 0, stream>>>(
            v_buf, nattr, Wsc1 + l * 4096, Wl11 + l * 4096, sc_v, xv_buf, N);
        edge_weights<<<(E + 63) / 64, 256, 0, stream>>>(
            edge_vec, Wfc1 + l * 640, Wfc2 + l * 8192, w_buf, y_buf, E);
        gather_msgs<<<(N + 3) / 4, 256, 0, stream>>>(
            off, cnt, eid, esrc, w_buf, y_buf, xs_buf, xv_buf, agg_s, agg_v, N);
        node_update_s<<<(N + 31) / 32, 256, 0, stream>>>(
            agg_s, nattr, Wl20 + l * 8192, sc_s, s_buf, snew, N);
        node_update_v<<<(N + 31) / 32, 256, 0, stream>>>(
            agg_v, nattr, Wl21 + l * 8192, sc_v, snew, v_buf, N);
    }

    float pool_scale = (float)(1.0 / sqrt((double)N / (double)NGRAPH));
    readout<<<(N + 15) / 64 / 4 * 4 + 4, 256, 0, stream>>>(
        s_buf, nattr, Wread, batch, (float*)d_out, N, pool_scale);
}

// Round 5
// 659.507 us; speedup vs baseline: 1.1792x; 1.1792x over previous
//
#include <hip/hip_runtime.h>
#include <math.h>

#define MUL 32
#define NATTR 4
#define NBASIS 10
#define HID 64
#define OUT_DIM 16
#define NGRAPH 8

#define PI_F 3.14159265358979323846f
#define SQRT3_F 1.7320508075688772f
#define INV_SQRT3_F 0.5773502691896258f
#define INV_SQRT10_F 0.31622776601683794f
#define INV_SQRTNN_F 0.17677669529663687f   // 1/sqrt(32)
#define NORM128_F 0.08838834764831845f      // 1/sqrt(128)
#define NORM256_F 0.0625f                   // 1/sqrt(256)
#define C_S_F 0.3826834323650898f           // sin(pi/8)
#define C_X_F 0.9238795325112867f           // cos(pi/8)
#define CSTEP_F (4.0f/9.0f)                 // linspace(0,4,10) step

// ---------------------------------------------------------------- init s,v
__global__ void init_sv(const float* __restrict__ x,
                        float* __restrict__ s, float* __restrict__ v, int N) {
    int i = blockIdx.x * 256 + threadIdx.x;
    if (i >= N * 128) return;
    int n = i >> 7, c = i & 127;
    float val = x[i];
    if (c < 32) s[n * 32 + c] = val;
    else        v[n * 96 + (c - 32)] = val;
}

// ---------------------------------------------------------------- CSR build
__global__ void csr_count(const int* __restrict__ edst, int* __restrict__ cnt, int E) {
    int e = blockIdx.x * 256 + threadIdx.x;
    if (e < E) atomicAdd(&cnt[edst[e]], 1);
}

__global__ void csr_scan(const int* __restrict__ cnt, int* __restrict__ off,
                         int* __restrict__ cursor, int N) {
    __shared__ int sums[256];
    int t = threadIdx.x;
    int chunk = (N + 255) / 256;
    int lo = t * chunk, hi = lo + chunk; if (hi > N) hi = N;
    int s = 0;
    for (int i = lo; i < hi; i++) s += cnt[i];
    sums[t] = s;
    __syncthreads();
    for (int d = 1; d < 256; d <<= 1) {
        int v = (t >= d) ? sums[t - d] : 0;
        __syncthreads();
        sums[t] += v;
        __syncthreads();
    }
    int run = (t == 0) ? 0 : sums[t - 1];
    for (int i = lo; i < hi; i++) {
        off[i] = run; cursor[i] = run;
        run += cnt[i];
    }
}

__global__ void csr_fill(const int* __restrict__ edst, int* __restrict__ cursor,
                         int* __restrict__ eid, int E) {
    int e = blockIdx.x * 256 + threadIdx.x;
    if (e < E) { int p = atomicAdd(&cursor[edst[e]], 1); eid[p] = e; }
}

// ------------------------------------------- node fctp, scalar path (s -> 2 outputs)
// 32 nodes/block (4 sub-batches of 8) to amortize the 32KB weight load.
__global__ __launch_bounds__(256, 2) void node_s_fctp(
    const float* __restrict__ s, const float* __restrict__ attr,
    const float* __restrict__ W0, const float* __restrict__ W1,
    float* __restrict__ out0, float* __restrict__ out1, int N) {
    __shared__ float w0[4096], w1[4096];
    __shared__ float sh_s[8][32];
    int ln = threadIdx.x >> 5, w = threadIdx.x & 31;
    for (int i = threadIdx.x; i < 4096; i += 256) { w0[i] = W0[i]; w1[i] = W1[i]; }
    for (int g = 0; g < 4; g++) {
        int n = blockIdx.x * 32 + g * 8 + ln;
        bool valid = n < N;
        __syncthreads();
        if (valid) sh_s[ln][w] = s[n * 32 + w];
        __syncthreads();
        if (!valid) continue;
        float4 at = *(const float4*)(attr + n * 4);
        float fa[4] = {at.x, at.y, at.z, at.w};
        float acc0 = 0.f, acc1 = 0.f;
        for (int u = 0; u < 32; u++) {
            float su = sh_s[ln][u];
            int base = u * 128 + w;
#pragma unroll
            for (int a = 0; a < 4; a++) {
                float c = su * fa[a];
                acc0 += c * w0[base + a * 32];
                acc1 += c * w1[base + a * 32];
            }
        }
        out0[n * 32 + w] = acc0 * NORM128_F;
        out1[n * 32 + w] = acc1 * NORM128_F;
    }
}

// ------------------------------------------- node fctp, vector path (v -> 2 outputs)
__global__ __launch_bounds__(256, 2) void node_v_fctp(
    const float* __restrict__ v, const float* __restrict__ attr,
    const float* __restrict__ W0, const float* __restrict__ W1,
    float* __restrict__ out0, float* __restrict__ out1, int N) {
    __shared__ float w0[4096], w1[4096];
    __shared__ float sh_v[8][96];
    int ln = threadIdx.x >> 5, w = threadIdx.x & 31;
    for (int i = threadIdx.x; i < 4096; i += 256) { w0[i] = W0[i]; w1[i] = W1[i]; }
    for (int g = 0; g < 4; g++) {
        int n = blockIdx.x * 32 + g * 8 + ln;
        bool valid = n < N;
        __syncthreads();
        if (valid) {
            sh_v[ln][w * 3 + 0] = v[n * 96 + w * 3 + 0];
            sh_v[ln][w * 3 + 1] = v[n * 96 + w * 3 + 1];
            sh_v[ln][w * 3 + 2] = v[n * 96 + w * 3 + 2];
        }
        __syncthreads();
        if (!valid) continue;
        float4 at = *(const float4*)(attr + n * 4);
        float fa[4] = {at.x, at.y, at.z, at.w};
        float a00 = 0, a01 = 0, a02 = 0, a10 = 0, a11 = 0, a12 = 0;
        for (int u = 0; u < 32; u++) {
            float vu0 = sh_v[ln][u * 3 + 0];
            float vu1 = sh_v[ln][u * 3 + 1];
            float vu2 = sh_v[ln][u * 3 + 2];
            int base = u * 128 + w;
#pragma unroll
            for (int a = 0; a < 4; a++) {
                float f = fa[a];
                float c0 = vu0 * f, c1 = vu1 * f, c2 = vu2 * f;
                float W0v = w0[base + a * 32], W1v = w1[base + a * 32];
                a00 += c0 * W0v; a01 += c1 * W0v; a02 += c2 * W0v;
                a10 += c0 * W1v; a11 += c1 * W1v; a12 += c2 * W1v;
            }
        }
        out0[n * 96 + w * 3 + 0] = a00 * NORM128_F;
        out0[n * 96 + w * 3 + 1] = a01 * NORM128_F;
        out0[n * 96 + w * 3 + 2] = a02 * NORM128_F;
        out1[n * 96 + w * 3 + 0] = a10 * NORM128_F;
        out1[n * 96 + w * 3 + 1] = a11 * NORM128_F;
        out1[n * 96 + w * 3 + 2] = a12 * NORM128_F;
    }
}

// ---------------------------------------------------------------- edge weights
// 64 edges/block: emb -> h (silu) -> w. Natural layout w_buf[e][wq]; each
// thread's 8 output channels are contiguous -> two direct float4 stores.
__global__ __launch_bounds__(256, 4) void edge_weights(
    const float* __restrict__ edge_vec,
    const float* __restrict__ Wfc1, const float* __restrict__ Wfc2,
    float* __restrict__ w_buf, float* __restrict__ y_buf, int E) {
    __shared__ float sh_wfc1[NBASIS * 64];   // [j][k]
    __shared__ float sh_embT[NBASIS * 64];   // [j][e]
    __shared__ float sh_h[64 * 65];          // [e][k], stride 65

    int tid = threadIdx.x;
    int e0 = blockIdx.x * 64;

    for (int i = tid; i < 640; i += 256) sh_wfc1[i] = Wfc1[i];
    if (tid < 64) {
        int e = e0 + tid;
        float ex = 0.f, ey = 0.f, ez = 0.f;
        if (e < E) {
            ex = edge_vec[e * 3 + 0]; ey = edge_vec[e * 3 + 1]; ez = edge_vec[e * 3 + 2];
        }
        float len = sqrtf(ex * ex + ey * ey + ez * ez);
        float rinv = SQRT3_F / (len + 1e-9f);
        if (e < E) {
            float4 y4 = {ex * rinv, ey * rinv, ez * rinv, len};
            *(float4*)(y_buf + (size_t)e * 4) = y4;
        }
        float uu = 2.0f * (len * 0.25f - 1.0f);
        float cut = (uu > 0.0f) ? 0.0f
                  : ((uu < -1.0f) ? 1.0f : 0.5f * (1.0f - __cosf(PI_F * uu)));
#pragma unroll
        for (int j = 0; j < NBASIS; j++) {
            float d = (len - j * CSTEP_F) * 2.5f;
            sh_embT[j * 64 + tid] = __expf(-d * d) * cut;
        }
    }
    __syncthreads();

    // ---- phase 1: h[e][k] = silu((emb @ Wfc1)/sqrt(10))
    {
        int k = tid & 63;
        int eb = (tid >> 6) * 16;
        float acc[16];
#pragma unroll
        for (int i = 0; i < 16; i++) acc[i] = 0.f;
#pragma unroll
        for (int j = 0; j < NBASIS; j++) {
            float wv = sh_wfc1[j * 64 + k];
#pragma unroll
            for (int i = 0; i < 16; i++) acc[i] += wv * sh_embT[j * 64 + eb + i];
        }
#pragma unroll
        for (int i = 0; i < 16; i++) {
            float a = acc[i] * INV_SQRT10_F;
            sh_h[(eb + i) * 65 + k] = a / (1.0f + __expf(-a));
        }
    }
    __syncthreads();

    // ---- phase 2: w[e][wq] = (h @ Wfc2)/8 ; tile 4 edges x 8 outputs;
    // direct float4 stores (16 lanes x 32B = 512B contiguous per edge group).
    {
        int wt = tid & 15;   // outputs wt*8 .. wt*8+7
        int et = tid >> 4;   // edges  et*4 .. et*4+3
        float acc[4][8];
#pragma unroll
        for (int ie = 0; ie < 4; ie++)
#pragma unroll
            for (int j = 0; j < 8; j++) acc[ie][j] = 0.f;
        const float* W2 = Wfc2 + wt * 8;
#pragma unroll 4
        for (int k = 0; k < HID; k++) {
            float4 b0 = *(const float4*)(W2 + k * 128);
            float4 b1 = *(const float4*)(W2 + k * 128 + 4);
            float bv[8] = {b0.x, b0.y, b0.z, b0.w, b1.x, b1.y, b1.z, b1.w};
            float hv[4];
#pragma unroll
            for (int ie = 0; ie < 4; ie++) hv[ie] = sh_h[(et * 4 + ie) * 65 + k];
#pragma unroll
            for (int ie = 0; ie < 4; ie++)
#pragma unroll
                for (int j = 0; j < 8; j++) acc[ie][j] += hv[ie] * bv[j];
        }
#pragma unroll
        for (int ie = 0; ie < 4; ie++) {
            int e = e0 + et * 4 + ie;
            if (e >= E) continue;
            float4 lo = {acc[ie][0] * 0.125f, acc[ie][1] * 0.125f,
                         acc[ie][2] * 0.125f, acc[ie][3] * 0.125f};
            float4 hi = {acc[ie][4] * 0.125f, acc[ie][5] * 0.125f,
                         acc[ie][6] * 0.125f, acc[ie][7] * 0.125f};
            float* dst = w_buf + (size_t)e * 128 + wt * 8;
            *(float4*)(dst)     = lo;
            *(float4*)(dst + 4) = hi;
        }
    }
}

// ---------------------------------------------------------------- gather
// one wave per dst node; half-wave per edge; lane u = channel u (0..31).
// w_buf natural layout: w[e][c*32+u] -> 4 coalesced dword loads per edge.
__global__ __launch_bounds__(256, 4) void gather_msgs(
    const int* __restrict__ off, const int* __restrict__ cnt,
    const int* __restrict__ eid, const int* __restrict__ esrc,
    const float* __restrict__ w_buf, const float* __restrict__ y_buf,
    const float* __restrict__ xs, const float* __restrict__ xv,
    float* __restrict__ agg_s, float* __restrict__ agg_v, int N) {
    int node = blockIdx.x * 4 + (threadIdx.x >> 6);
    if (node >= N) return;
    int lane = threadIdx.x & 63;
    int half = lane >> 5;
    int u = lane & 31;
    int o = off[node], deg = cnt[node];
    float as0 = 0, as1 = 0;
    float av00 = 0, av01 = 0, av02 = 0, av10 = 0, av11 = 0, av12 = 0;
    for (int i = half; i < deg; i += 2) {
        int e = eid[o + i];
        int src = esrc[e];
        const float* wp = w_buf + (size_t)e * 128 + u;
        float wa = wp[0], wb = wp[32], wc = wp[64], wd = wp[96];
        float4 y  = *(const float4*)(y_buf + (size_t)e * 4);
        float sE = xs[src * 32 + u];
        const float* vp = xv + src * 96 + u * 3;
        float v0 = vp[0], v1 = vp[1], v2 = vp[2];
        as0 += wa * sE;
        as1 += wb * (y.x * v0 + y.y * v1 + y.z * v2) * INV_SQRT3_F;
        float t = wc * sE;
        av00 += t * y.x;  av01 += t * y.y;  av02 += t * y.z;
        av10 += wd * v0; av11 += wd * v1; av12 += wd * v2;
    }
    as0 += __shfl_down(as0, 32);  as1 += __shfl_down(as1, 32);
    av00 += __shfl_down(av00, 32); av01 += __shfl_down(av01, 32); av02 += __shfl_down(av02, 32);
    av10 += __shfl_down(av10, 32); av11 += __shfl_down(av11, 32); av12 += __shfl_down(av12, 32);
    if (half == 0) {
        agg_s[node * 64 + u]      = as0 * INV_SQRTNN_F;
        agg_s[node * 64 + 32 + u] = as1 * INV_SQRTNN_F;
        float* av = agg_v + (size_t)node * 192;
        av[u * 3 + 0]      = av00 * INV_SQRTNN_F;
        av[u * 3 + 1]      = av01 * INV_SQRTNN_F;
        av[u * 3 + 2]      = av02 * INV_SQRTNN_F;
        av[96 + u * 3 + 0] = av10 * INV_SQRTNN_F;
        av[96 + u * 3 + 1] = av11 * INV_SQRTNN_F;
        av[96 + u * 3 + 2] = av12 * INV_SQRTNN_F;
    }
}

// ------------------------------------------- second fctp (64-wide) + s update
__global__ __launch_bounds__(256, 2) void node_update_s(
    const float* __restrict__ agg_s, const float* __restrict__ attr,
    const float* __restrict__ W0, const float* __restrict__ sc_s,
    float* __restrict__ s, float* __restrict__ snew, int N) {
    __shared__ float w0[8192];
    __shared__ float sh_as[8][64];
    int ln = threadIdx.x >> 5, w = threadIdx.x & 31;
    for (int i = threadIdx.x; i < 8192; i += 256) w0[i] = W0[i];
    for (int g = 0; g < 4; g++) {
        int n = blockIdx.x * 32 + g * 8 + ln;
        bool valid = n < N;
        __syncthreads();
        if (valid) {
            sh_as[ln][w] = agg_s[n * 64 + w];
            sh_as[ln][32 + w] = agg_s[n * 64 + 32 + w];
        }
        __syncthreads();
        if (!valid) continue;
        float4 at = *(const float4*)(attr + n * 4);
        float fa[4] = {at.x, at.y, at.z, at.w};
        float acc = 0.f;
        for (int u = 0; u < 64; u++) {
            float g_ = sh_as[ln][u];
            int base = u * 128 + w;
#pragma unroll
            for (int a = 0; a < 4; a++) acc += g_ * fa[a] * w0[base + a * 32];
        }
        float os = acc * NORM256_F;
        float sn = C_S_F * sc_s[n * 32 + w] + C_X_F * os;
        snew[n * 32 + w] = sn;
        float sig = 1.0f / (1.0f + __expf(-sn));
        s[n * 32 + w] += sn * sig;   // silu(sn)
    }
}

// ------------------------------------------- second fctp (64-wide) + v update
__global__ __launch_bounds__(256, 2) void node_update_v(
    const float* __restrict__ agg_v, const float* __restrict__ attr,
    const float* __restrict__ W1, const float* __restrict__ sc_v,
    const float* __restrict__ snew, float* __restrict__ v, int N) {
    __shared__ float w1[8192];
    __shared__ float sh_av[8][192];
    int ln = threadIdx.x >> 5, w = threadIdx.x & 31;
    for (int i = threadIdx.x; i < 8192; i += 256) w1[i] = W1[i];
    for (int g = 0; g < 4; g++) {
        int n = blockIdx.x * 32 + g * 8 + ln;
        bool valid = n < N;
        __syncthreads();
        if (valid) {
#pragma unroll
            for (int i = 0; i < 6; i++)
                sh_av[ln][w * 6 + i] = agg_v[(size_t)n * 192 + w * 6 + i];
        }
        __syncthreads();
        if (!valid) continue;
        float4 at = *(const float4*)(attr + n * 4);
        float fa[4] = {at.x, at.y, at.z, at.w};
        float a0 = 0.f, a1 = 0.f, a2 = 0.f;
        for (int u = 0; u < 64; u++) {
            float g0 = sh_av[ln][u * 3 + 0];
            float g1 = sh_av[ln][u * 3 + 1];
            float g2 = sh_av[ln][u * 3 + 2];
            int base = u * 128 + w;
#pragma unroll
            for (int a = 0; a < 4; a++) {
                float f = fa[a];
                float W1v = w1[base + a * 32];
                a0 += g0 * f * W1v; a1 += g1 * f * W1v; a2 += g2 * f * W1v;
            }
        }
        float sn = snew[n * 32 + w];
        float sig = 1.0f / (1.0f + __expf(-sn));
        float ov0 = a0 * NORM256_F, ov1 = a1 * NORM256_F, ov2 = a2 * NORM256_F;
        v[n * 96 + w * 3 + 0] += (C_S_F * sc_v[n * 96 + w * 3 + 0] + C_X_F * ov0) * sig;
        v[n * 96 + w * 3 + 1] += (C_S_F * sc_v[n * 96 + w * 3 + 1] + C_X_F * ov1) * sig;
        v[n * 96 + w * 3 + 2] += (C_S_F * sc_v[n * 96 + w * 3 + 2] + C_X_F * ov2) * sig;
    }
}

// ---------------------------------------------------------------- readout
// 64 nodes/block; per-block LDS reduction kills the 128-address atomic storm.
__global__ __launch_bounds__(256) void readout(
    const float* __restrict__ s, const float* __restrict__ attr,
    const float* __restrict__ Wread, const int* __restrict__ batch,
    float* __restrict__ out, int N, float pool_scale) {
    __shared__ float wr[2048];
    __shared__ float red[NGRAPH * 16];
    for (int i = threadIdx.x; i < 2048; i += 256) wr[i] = Wread[i];
    if (threadIdx.x < NGRAPH * 16) red[threadIdx.x] = 0.f;
    __syncthreads();
    int ln = threadIdx.x >> 4, w = threadIdx.x & 15;
    for (int g = 0; g < 4; g++) {
        int n = blockIdx.x * 64 + g * 16 + ln;
        if (n < N) {
            float4 at = *(const float4*)(attr + n * 4);
            float fa[4] = {at.x, at.y, at.z, at.w};
            float acc = 0.f;
            for (int u = 0; u < 32; u++) {
                float su = s[n * 32 + u];
                int base = u * 64 + w;
#pragma unroll
                for (int a = 0; a < 4; a++) acc += su * fa[a] * wr[base + a * 16];
            }
            atomicAdd(&red[batch[n] * 16 + w], acc);
        }
    }
    __syncthreads();
    if (threadIdx.x < NGRAPH * 16) {
        float val = red[threadIdx.x];
        if (val != 0.f)
            atomicAdd(&out[threadIdx.x], val * NORM128_F * pool_scale);
    }
}

// ---------------------------------------------------------------- launch
extern "C" void kernel_launch(void* const* d_in, const int* in_sizes, int n_in,
                              void* d_out, int out_size, void* d_ws, size_t ws_size,
                              hipStream_t stream) {
    const float* x        = (const float*)d_in[0];
    const float* nattr    = (const float*)d_in[1];
    const float* edge_vec = (const float*)d_in[2];
    const int*   batch    = (const int*)d_in[3];
    const int*   esrc     = (const int*)d_in[4];
    const int*   edst     = (const int*)d_in[5];
    const float* Wsc0  = (const float*)d_in[6];
    const float* Wsc1  = (const float*)d_in[7];
    const float* Wl10  = (const float*)d_in[8];
    const float* Wl11  = (const float*)d_in[9];
    const float* Wfc1  = (const float*)d_in[10];
    const float* Wfc2  = (const float*)d_in[11];
    const float* Wl20  = (const float*)d_in[12];
    const float* Wl21  = (const float*)d_in[13];
    const float* Wread = (const float*)d_in[14];

    int N = in_sizes[0] / (MUL * 4);
    int E = in_sizes[2] / 3;

    float* p = (float*)d_ws;
    float* w_buf  = p; p += (size_t)E * 128;   // natural layout [e][wq]
    float* y_buf  = p; p += (size_t)E * 4;
    float* s_buf  = p; p += (size_t)N * 32;
    float* v_buf  = p; p += (size_t)N * 96;
    float* sc_s   = p; p += (size_t)N * 32;
    float* sc_v   = p; p += (size_t)N * 96;
    float* xs_buf = p; p += (size_t)N * 32;
    float* xv_buf = p; p += (size_t)N * 96;
    float* snew   = p; p += (size_t)N * 32;
    float* agg_s  = p; p += (size_t)N * 64;
    float* agg_v  = p; p += (size_t)N * 192;
    int* cnt    = (int*)p; p += N;
    int* off    = (int*)p; p += N;
    int* cursor = (int*)p; p += N;
    int* eid    = (int*)p; p += E;

    init_sv<<<(N * 128 + 255) / 256, 256, 0, stream>>>(x, s_buf, v_buf, N);
    hipMemsetAsync(d_out, 0, (size_t)out_size * sizeof(float), stream);

    // CSR by destination
    hipMemsetAsync(cnt, 0, (size_t)N * sizeof(int), stream);
    csr_count<<<(E + 255) / 256, 256, 0, stream>>>(edst, cnt, E);
    csr_scan<<<1, 256, 0, stream>>>(cnt, off, cursor, N);
    csr_fill<<<(E + 255) / 256, 256, 0, stream>>>(edst, cursor, eid, E);

    for (int l = 0; l < 2; l++) {
        node_s_fctp<<<(N + 31) / 32, 256, 0, stream>>>(
            s_buf, nattr, Wsc0 + l * 4096, Wl10 + l * 4096, sc_s, xs_buf, N);
        node_v_fctp<<<(N + 31) / 32, 256, 0, stream>>>(
            v_buf, nattr, Wsc1 + l * 4096, Wl11 + l * 4096, sc_v, xv_buf, N);
        edge_weights<<<(E + 63) / 64, 256, 0, stream>>>(
            edge_vec, Wfc1 + l * 640, Wfc2 + l * 8192, w_buf, y_buf, E);
        gather_msgs<<<(N + 3) / 4, 256, 0, stream>>>(
            off, cnt, eid, esrc, w_buf, y_buf, xs_buf, xv_buf, agg_s, agg_v, N);
        node_update_s<<<(N + 31) / 32, 256, 0, stream>>>(
            agg_s, nattr, Wl20 + l * 8192, sc_s, s_buf, snew, N);
        node_update_v<<<(N + 31) / 32, 256, 0, stream>>>(
            agg_v, nattr, Wl21 + l * 8192, sc_v, snew, v_buf, N);
    }

    float pool_scale = (float)(1.0 / sqrt((double)N / (double)NGRAPH));
    readout<<<(N + 63) / 64, 256, 0, stream>>>(
        s_buf, nattr, Wread, batch, (float*)d_out, N, pool_scale);
}

// Round 6
// 631.951 us; speedup vs baseline: 1.2306x; 1.0436x over previous
//
#include <hip/hip_runtime.h>
#include <math.h>

#define MUL 32
#define NATTR 4
#define NBASIS 10
#define HID 64
#define OUT_DIM 16
#define NGRAPH 8

#define PI_F 3.14159265358979323846f
#define SQRT3_F 1.7320508075688772f
#define INV_SQRT3_F 0.5773502691896258f
#define INV_SQRT10_F 0.31622776601683794f
#define INV_SQRTNN_F 0.17677669529663687f   // 1/sqrt(32)
#define NORM128_F 0.08838834764831845f      // 1/sqrt(128)
#define NORM256_F 0.0625f                   // 1/sqrt(256)
#define C_S_F 0.3826834323650898f           // sin(pi/8)
#define C_X_F 0.9238795325112867f           // cos(pi/8)
#define CSTEP_F (4.0f/9.0f)                 // linspace(0,4,10) step

// ---------------------------------------------------------------- init s,v
__global__ void init_sv(const float* __restrict__ x,
                        float* __restrict__ s, float* __restrict__ v, int N) {
    int i = blockIdx.x * 256 + threadIdx.x;
    if (i >= N * 128) return;
    int n = i >> 7, c = i & 127;
    float val = x[i];
    if (c < 32) s[n * 32 + c] = val;
    else        v[n * 96 + (c - 32)] = val;
}

// ---------------------------------------------------------------- CSR build
__global__ void csr_count(const int* __restrict__ edst, int* __restrict__ cnt, int E) {
    int e = blockIdx.x * 256 + threadIdx.x;
    if (e < E) atomicAdd(&cnt[edst[e]], 1);
}

__global__ void csr_scan(const int* __restrict__ cnt, int* __restrict__ off,
                         int* __restrict__ cursor, int N) {
    __shared__ int sums[256];
    int t = threadIdx.x;
    int chunk = (N + 255) / 256;
    int lo = t * chunk, hi = lo + chunk; if (hi > N) hi = N;
    int s = 0;
    for (int i = lo; i < hi; i++) s += cnt[i];
    sums[t] = s;
    __syncthreads();
    for (int d = 1; d < 256; d <<= 1) {
        int v = (t >= d) ? sums[t - d] : 0;
        __syncthreads();
        sums[t] += v;
        __syncthreads();
    }
    int run = (t == 0) ? 0 : sums[t - 1];
    for (int i = lo; i < hi; i++) {
        off[i] = run; cursor[i] = run;
        run += cnt[i];
    }
}

// fill: scatter edge_vec and esrc into CSR slot order (kills all gather
// indirection downstream).
__global__ void csr_fill(const int* __restrict__ edst, const int* __restrict__ esrc,
                         const float* __restrict__ edge_vec,
                         int* __restrict__ cursor,
                         float* __restrict__ vec_csr, int* __restrict__ src_csr,
                         int E) {
    int e = blockIdx.x * 256 + threadIdx.x;
    if (e < E) {
        int p = atomicAdd(&cursor[edst[e]], 1);
        float4 vv = {edge_vec[e * 3 + 0], edge_vec[e * 3 + 1], edge_vec[e * 3 + 2], 0.f};
        *(float4*)(vec_csr + (size_t)p * 4) = vv;
        src_csr[p] = esrc[e];
    }
}

// ------------------------------------------- node fctp, scalar path (s -> 2 outputs)
// 32 nodes/block (4 sub-batches of 8) to amortize the 32KB weight load.
__global__ __launch_bounds__(256, 2) void node_s_fctp(
    const float* __restrict__ s, const float* __restrict__ attr,
    const float* __restrict__ W0, const float* __restrict__ W1,
    float* __restrict__ out0, float* __restrict__ out1, int N) {
    __shared__ float w0[4096], w1[4096];
    __shared__ float sh_s[8][32];
    int ln = threadIdx.x >> 5, w = threadIdx.x & 31;
    for (int i = threadIdx.x; i < 4096; i += 256) { w0[i] = W0[i]; w1[i] = W1[i]; }
    for (int g = 0; g < 4; g++) {
        int n = blockIdx.x * 32 + g * 8 + ln;
        bool valid = n < N;
        __syncthreads();
        if (valid) sh_s[ln][w] = s[n * 32 + w];
        __syncthreads();
        if (!valid) continue;
        float4 at = *(const float4*)(attr + n * 4);
        float fa[4] = {at.x, at.y, at.z, at.w};
        float acc0 = 0.f, acc1 = 0.f;
        for (int u = 0; u < 32; u++) {
            float su = sh_s[ln][u];
            int base = u * 128 + w;
#pragma unroll
            for (int a = 0; a < 4; a++) {
                float c = su * fa[a];
                acc0 += c * w0[base + a * 32];
                acc1 += c * w1[base + a * 32];
            }
        }
        out0[n * 32 + w] = acc0 * NORM128_F;
        out1[n * 32 + w] = acc1 * NORM128_F;
    }
}

// ------------------------------------------- node fctp, vector path (v -> 2 outputs)
__global__ __launch_bounds__(256, 2) void node_v_fctp(
    const float* __restrict__ v, const float* __restrict__ attr,
    const float* __restrict__ W0, const float* __restrict__ W1,
    float* __restrict__ out0, float* __restrict__ out1, int N) {
    __shared__ float w0[4096], w1[4096];
    __shared__ float sh_v[8][96];
    int ln = threadIdx.x >> 5, w = threadIdx.x & 31;
    for (int i = threadIdx.x; i < 4096; i += 256) { w0[i] = W0[i]; w1[i] = W1[i]; }
    for (int g = 0; g < 4; g++) {
        int n = blockIdx.x * 32 + g * 8 + ln;
        bool valid = n < N;
        __syncthreads();
        if (valid) {
            sh_v[ln][w * 3 + 0] = v[n * 96 + w * 3 + 0];
            sh_v[ln][w * 3 + 1] = v[n * 96 + w * 3 + 1];
            sh_v[ln][w * 3 + 2] = v[n * 96 + w * 3 + 2];
        }
        __syncthreads();
        if (!valid) continue;
        float4 at = *(const float4*)(attr + n * 4);
        float fa[4] = {at.x, at.y, at.z, at.w};
        float a00 = 0, a01 = 0, a02 = 0, a10 = 0, a11 = 0, a12 = 0;
        for (int u = 0; u < 32; u++) {
            float vu0 = sh_v[ln][u * 3 + 0];
            float vu1 = sh_v[ln][u * 3 + 1];
            float vu2 = sh_v[ln][u * 3 + 2];
            int base = u * 128 + w;
#pragma unroll
            for (int a = 0; a < 4; a++) {
                float f = fa[a];
                float c0 = vu0 * f, c1 = vu1 * f, c2 = vu2 * f;
                float W0v = w0[base + a * 32], W1v = w1[base + a * 32];
                a00 += c0 * W0v; a01 += c1 * W0v; a02 += c2 * W0v;
                a10 += c0 * W1v; a11 += c1 * W1v; a12 += c2 * W1v;
            }
        }
        out0[n * 96 + w * 3 + 0] = a00 * NORM128_F;
        out0[n * 96 + w * 3 + 1] = a01 * NORM128_F;
        out0[n * 96 + w * 3 + 2] = a02 * NORM128_F;
        out1[n * 96 + w * 3 + 0] = a10 * NORM128_F;
        out1[n * 96 + w * 3 + 1] = a11 * NORM128_F;
        out1[n * 96 + w * 3 + 2] = a12 * NORM128_F;
    }
}

// ---------------------------------------------------------------- edge weights
// 64 CSR slots/block: streaming vec_csr -> emb -> h (silu) -> w.
// All I/O (vec_csr, y_buf, w_buf) is CSR-slot indexed and fully streaming.
__global__ __launch_bounds__(256, 4) void edge_weights(
    const float* __restrict__ vec_csr,
    const float* __restrict__ Wfc1, const float* __restrict__ Wfc2,
    float* __restrict__ w_buf, float* __restrict__ y_buf, int E) {
    __shared__ float sh_wfc1[NBASIS * 64];   // [j][k]
    __shared__ float sh_embT[NBASIS * 64];   // [j][e]
    __shared__ float sh_h[64 * 65];          // [e][k], stride 65

    int tid = threadIdx.x;
    int e0 = blockIdx.x * 64;

    for (int i = tid; i < 640; i += 256) sh_wfc1[i] = Wfc1[i];
    if (tid < 64) {
        int e = e0 + tid;
        float ex = 0.f, ey = 0.f, ez = 0.f;
        if (e < E) {
            float4 vv = *(const float4*)(vec_csr + (size_t)e * 4);
            ex = vv.x; ey = vv.y; ez = vv.z;
        }
        float len = sqrtf(ex * ex + ey * ey + ez * ez);
        float rinv = SQRT3_F / (len + 1e-9f);
        if (e < E) {
            float4 y4 = {ex * rinv, ey * rinv, ez * rinv, len};
            *(float4*)(y_buf + (size_t)e * 4) = y4;
        }
        float uu = 2.0f * (len * 0.25f - 1.0f);
        float cut = (uu > 0.0f) ? 0.0f
                  : ((uu < -1.0f) ? 1.0f : 0.5f * (1.0f - __cosf(PI_F * uu)));
#pragma unroll
        for (int j = 0; j < NBASIS; j++) {
            float d = (len - j * CSTEP_F) * 2.5f;
            sh_embT[j * 64 + tid] = __expf(-d * d) * cut;
        }
    }
    __syncthreads();

    // ---- phase 1: h[e][k] = silu((emb @ Wfc1)/sqrt(10))
    {
        int k = tid & 63;
        int eb = (tid >> 6) * 16;
        float acc[16];
#pragma unroll
        for (int i = 0; i < 16; i++) acc[i] = 0.f;
#pragma unroll
        for (int j = 0; j < NBASIS; j++) {
            float wv = sh_wfc1[j * 64 + k];
#pragma unroll
            for (int i = 0; i < 16; i++) acc[i] += wv * sh_embT[j * 64 + eb + i];
        }
#pragma unroll
        for (int i = 0; i < 16; i++) {
            float a = acc[i] * INV_SQRT10_F;
            sh_h[(eb + i) * 65 + k] = a / (1.0f + __expf(-a));
        }
    }
    __syncthreads();

    // ---- phase 2: w[e][wq] = (h @ Wfc2)/8 ; tile 4 edges x 8 outputs;
    // direct float4 stores (16 lanes x 32B = 512B contiguous per edge group).
    {
        int wt = tid & 15;   // outputs wt*8 .. wt*8+7
        int et = tid >> 4;   // edges  et*4 .. et*4+3
        float acc[4][8];
#pragma unroll
        for (int ie = 0; ie < 4; ie++)
#pragma unroll
            for (int j = 0; j < 8; j++) acc[ie][j] = 0.f;
        const float* W2 = Wfc2 + wt * 8;
#pragma unroll 4
        for (int k = 0; k < HID; k++) {
            float4 b0 = *(const float4*)(W2 + k * 128);
            float4 b1 = *(const float4*)(W2 + k * 128 + 4);
            float bv[8] = {b0.x, b0.y, b0.z, b0.w, b1.x, b1.y, b1.z, b1.w};
            float hv[4];
#pragma unroll
            for (int ie = 0; ie < 4; ie++) hv[ie] = sh_h[(et * 4 + ie) * 65 + k];
#pragma unroll
            for (int ie = 0; ie < 4; ie++)
#pragma unroll
                for (int j = 0; j < 8; j++) acc[ie][j] += hv[ie] * bv[j];
        }
#pragma unroll
        for (int ie = 0; ie < 4; ie++) {
            int e = e0 + et * 4 + ie;
            if (e >= E) continue;
            float4 lo = {acc[ie][0] * 0.125f, acc[ie][1] * 0.125f,
                         acc[ie][2] * 0.125f, acc[ie][3] * 0.125f};
            float4 hi = {acc[ie][4] * 0.125f, acc[ie][5] * 0.125f,
                         acc[ie][6] * 0.125f, acc[ie][7] * 0.125f};
            float* dst = w_buf + (size_t)e * 128 + wt * 8;
            *(float4*)(dst)     = lo;
            *(float4*)(dst + 4) = hi;
        }
    }
}

// ---------------------------------------------------------------- gather
// one wave per dst node; half-wave per edge-slot; lane u = channel u.
// ALL edge-side arrays (w_buf, y_buf, src_csr) are CSR-ordered -> pure
// streaming reads, zero indirection; only xs/xv are random (L2-resident).
__global__ __launch_bounds__(256, 4) void gather_msgs(
    const int* __restrict__ off, const int* __restrict__ cnt,
    const int* __restrict__ src_csr,
    const float* __restrict__ w_buf, const float* __restrict__ y_buf,
    const float* __restrict__ xs, const float* __restrict__ xv,
    float* __restrict__ agg_s, float* __restrict__ agg_v, int N) {
    int node = blockIdx.x * 4 + (threadIdx.x >> 6);
    if (node >= N) return;
    int lane = threadIdx.x & 63;
    int half = lane >> 5;
    int u = lane & 31;
    int o = off[node], deg = cnt[node];
    float as0 = 0, as1 = 0;
    float av00 = 0, av01 = 0, av02 = 0, av10 = 0, av11 = 0, av12 = 0;
    for (int i = half; i < deg; i += 2) {
        size_t p = (size_t)(o + i);
        int src = src_csr[p];
        const float* wp = w_buf + p * 128 + u;
        float wa = wp[0], wb = wp[32], wc = wp[64], wd = wp[96];
        float4 y  = *(const float4*)(y_buf + p * 4);
        float sE = xs[src * 32 + u];
        const float* vp = xv + src * 96 + u * 3;
        float v0 = vp[0], v1 = vp[1], v2 = vp[2];
        as0 += wa * sE;
        as1 += wb * (y.x * v0 + y.y * v1 + y.z * v2) * INV_SQRT3_F;
        float t = wc * sE;
        av00 += t * y.x;  av01 += t * y.y;  av02 += t * y.z;
        av10 += wd * v0; av11 += wd * v1; av12 += wd * v2;
    }
    as0 += __shfl_down(as0, 32);  as1 += __shfl_down(as1, 32);
    av00 += __shfl_down(av00, 32); av01 += __shfl_down(av01, 32); av02 += __shfl_down(av02, 32);
    av10 += __shfl_down(av10, 32); av11 += __shfl_down(av11, 32); av12 += __shfl_down(av12, 32);
    if (half == 0) {
        agg_s[node * 64 + u]      = as0 * INV_SQRTNN_F;
        agg_s[node * 64 + 32 + u] = as1 * INV_SQRTNN_F;
        float* av = agg_v + (size_t)node * 192;
        av[u * 3 + 0]      = av00 * INV_SQRTNN_F;
        av[u * 3 + 1]      = av01 * INV_SQRTNN_F;
        av[u * 3 + 2]      = av02 * INV_SQRTNN_F;
        av[96 + u * 3 + 0] = av10 * INV_SQRTNN_F;
        av[96 + u * 3 + 1] = av11 * INV_SQRTNN_F;
        av[96 + u * 3 + 2] = av12 * INV_SQRTNN_F;
    }
}

// ------------------------------------------- second fctp (64-wide) + s update
__global__ __launch_bounds__(256, 2) void node_update_s(
    const float* __restrict__ agg_s, const float* __restrict__ attr,
    const float* __restrict__ W0, const float* __restrict__ sc_s,
    float* __restrict__ s, float* __restrict__ snew, int N) {
    __shared__ float w0[8192];
    __shared__ float sh_as[8][64];
    int ln = threadIdx.x >> 5, w = threadIdx.x & 31;
    for (int i = threadIdx.x; i < 8192; i += 256) w0[i] = W0[i];
    for (int g = 0; g < 4; g++) {
        int n = blockIdx.x * 32 + g * 8 + ln;
        bool valid = n < N;
        __syncthreads();
        if (valid) {
            sh_as[ln][w] = agg_s[n * 64 + w];
            sh_as[ln][32 + w] = agg_s[n * 64 + 32 + w];
        }
        __syncthreads();
        if (!valid) continue;
        float4 at = *(const float4*)(attr + n * 4);
        float fa[4] = {at.x, at.y, at.z, at.w};
        float acc = 0.f;
        for (int u = 0; u < 64; u++) {
            float g_ = sh_as[ln][u];
            int base = u * 128 + w;
#pragma unroll
            for (int a = 0; a < 4; a++) acc += g_ * fa[a] * w0[base + a * 32];
        }
        float os = acc * NORM256_F;
        float sn = C_S_F * sc_s[n * 32 + w] + C_X_F * os;
        snew[n * 32 + w] = sn;
        float sig = 1.0f / (1.0f + __expf(-sn));
        s[n * 32 + w] += sn * sig;   // silu(sn)
    }
}

// ------------------------------------------- second fctp (64-wide) + v update
__global__ __launch_bounds__(256, 2) void node_update_v(
    const float* __restrict__ agg_v, const float* __restrict__ attr,
    const float* __restrict__ W1, const float* __restrict__ sc_v,
    const float* __restrict__ snew, float* __restrict__ v, int N) {
    __shared__ float w1[8192];
    __shared__ float sh_av[8][192];
    int ln = threadIdx.x >> 5, w = threadIdx.x & 31;
    for (int i = threadIdx.x; i < 8192; i += 256) w1[i] = W1[i];
    for (int g = 0; g < 4; g++) {
        int n = blockIdx.x * 32 + g * 8 + ln;
        bool valid = n < N;
        __syncthreads();
        if (valid) {
#pragma unroll
            for (int i = 0; i < 6; i++)
                sh_av[ln][w * 6 + i] = agg_v[(size_t)n * 192 + w * 6 + i];
        }
        __syncthreads();
        if (!valid) continue;
        float4 at = *(const float4*)(attr + n * 4);
        float fa[4] = {at.x, at.y, at.z, at.w};
        float a0 = 0.f, a1 = 0.f, a2 = 0.f;
        for (int u = 0; u < 64; u++) {
            float g0 = sh_av[ln][u * 3 + 0];
            float g1 = sh_av[ln][u * 3 + 1];
            float g2 = sh_av[ln][u * 3 + 2];
            int base = u * 128 + w;
#pragma unroll
            for (int a = 0; a < 4; a++) {
                float f = fa[a];
                float W1v = w1[base + a * 32];
                a0 += g0 * f * W1v; a1 += g1 * f * W1v; a2 += g2 * f * W1v;
            }
        }
        float sn = snew[n * 32 + w];
        float sig = 1.0f / (1.0f + __expf(-sn));
        float ov0 = a0 * NORM256_F, ov1 = a1 * NORM256_F, ov2 = a2 * NORM256_F;
        v[n * 96 + w * 3 + 0] += (C_S_F * sc_v[n * 96 + w * 3 + 0] + C_X_F * ov0) * sig;
        v[n * 96 + w * 3 + 1] += (C_S_F * sc_v[n * 96 + w * 3 + 1] + C_X_F * ov1) * sig;
        v[n * 96 + w * 3 + 2] += (C_S_F * sc_v[n * 96 + w * 3 + 2] + C_X_F * ov2) * sig;
    }
}

// ---------------------------------------------------------------- readout
// 64 nodes/block; per-block LDS reduction kills the 128-address atomic storm.
__global__ __launch_bounds__(256) void readout(
    const float* __restrict__ s, const float* __restrict__ attr,
    const float* __restrict__ Wread, const int* __restrict__ batch,
    float* __restrict__ out, int N, float pool_scale) {
    __shared__ float wr[2048];
    __shared__ float red[NGRAPH * 16];
    for (int i = threadIdx.x; i < 2048; i += 256) wr[i] = Wread[i];
    if (threadIdx.x < NGRAPH * 16) red[threadIdx.x] = 0.f;
    __syncthreads();
    int ln = threadIdx.x >> 4, w = threadIdx.x & 15;
    for (int g = 0; g < 4; g++) {
        int n = blockIdx.x * 64 + g * 16 + ln;
        if (n < N) {
            float4 at = *(const float4*)(attr + n * 4);
            float fa[4] = {at.x, at.y, at.z, at.w};
            float acc = 0.f;
            for (int u = 0; u < 32; u++) {
                float su = s[n * 32 + u];
                int base = u * 64 + w;
#pragma unroll
                for (int a = 0; a < 4; a++) acc += su * fa[a] * wr[base + a * 16];
            }
            atomicAdd(&red[batch[n] * 16 + w], acc);
        }
    }
    __syncthreads();
    if (threadIdx.x < NGRAPH * 16) {
        float val = red[threadIdx.x];
        if (val != 0.f)
            atomicAdd(&out[threadIdx.x], val * NORM128_F * pool_scale);
    }
}

// ---------------------------------------------------------------- launch
extern "C" void kernel_launch(void* const* d_in, const int* in_sizes, int n_in,
                              void* d_out, int out_size, void* d_ws, size_t ws_size,
                              hipStream_t stream) {
    const float* x        = (const float*)d_in[0];
    const float* nattr    = (const float*)d_in[1];
    const float* edge_vec = (const float*)d_in[2];
    const int*   batch    = (const int*)d_in[3];
    const int*   esrc     = (const int*)d_in[4];
    const int*   edst     = (const int*)d_in[5];
    const float* Wsc0  = (const float*)d_in[6];
    const float* Wsc1  = (const float*)d_in[7];
    const float* Wl10  = (const float*)d_in[8];
    const float* Wl11  = (const float*)d_in[9];
    const float* Wfc1  = (const float*)d_in[10];
    const float* Wfc2  = (const float*)d_in[11];
    const float* Wl20  = (const float*)d_in[12];
    const float* Wl21  = (const float*)d_in[13];
    const float* Wread = (const float*)d_in[14];

    int N = in_sizes[0] / (MUL * 4);
    int E = in_sizes[2] / 3;

    float* p = (float*)d_ws;
    float* w_buf   = p; p += (size_t)E * 128;   // CSR-slot indexed [p][wq]
    float* y_buf   = p; p += (size_t)E * 4;     // CSR-slot indexed
    float* vec_csr = p; p += (size_t)E * 4;     // CSR-slot indexed edge vectors
    float* s_buf  = p; p += (size_t)N * 32;
    float* v_buf  = p; p += (size_t)N * 96;
    float* sc_s   = p; p += (size_t)N * 32;
    float* sc_v   = p; p += (size_t)N * 96;
    float* xs_buf = p; p += (size_t)N * 32;
    float* xv_buf = p; p += (size_t)N * 96;
    float* snew   = p; p += (size_t)N * 32;
    float* agg_s  = p; p += (size_t)N * 64;
    float* agg_v  = p; p += (size_t)N * 192;
    int* cnt     = (int*)p; p += N;
    int* off     = (int*)p; p += N;
    int* cursor  = (int*)p; p += N;
    int* src_csr = (int*)p; p += E;

    init_sv<<<(N * 128 + 255) / 256, 256, 0, stream>>>(x, s_buf, v_buf, N);
    hipMemsetAsync(d_out, 0, (size_t)out_size * sizeof(float), stream);

    // CSR by destination; edge data scattered into CSR order once.
    hipMemsetAsync(cnt, 0, (size_t)N * sizeof(int), stream);
    csr_count<<<(E + 255) / 256, 256, 0, stream>>>(edst, cnt, E);
    csr_scan<<<1, 256, 0, stream>>>(cnt, off, cursor, N);
    csr_fill<<<(E + 255) / 256, 256, 0, stream>>>(
        edst, esrc, edge_vec, cursor, vec_csr, src_csr, E);

    for (int l = 0; l < 2; l++) {
        node_s_fctp<<<(N + 31) / 32, 256, 0, stream>>>(
            s_buf, nattr, Wsc0 + l * 4096, Wl10 + l * 4096, sc_s, xs_buf, N);
        node_v_fctp<<<(N + 31) / 32, 256, 0, stream>>>(
            v_buf, nattr, Wsc1 + l * 4096, Wl11 + l * 4096, sc_v, xv_buf, N);
        edge_weights<<<(E + 63) / 64, 256, 0, stream>>>(
            vec_csr, Wfc1 + l * 640, Wfc2 + l * 8192, w_buf, y_buf, E);
        gather_msgs<<<(N + 3) / 4, 256, 0, stream>>>(
            off, cnt, src_csr, w_buf, y_buf, xs_buf, xv_buf, agg_s, agg_v, N);
        node_update_s<<<(N + 31) / 32, 256, 0, stream>>>(
            agg_s, nattr, Wl20 + l * 8192, sc_s, s_buf, snew, N);
        node_update_v<<<(N + 31) / 32, 256, 0, stream>>>(
            agg_v, nattr, Wl21 + l * 8192, sc_v, snew, v_buf, N);
    }

    float pool_scale = (float)(1.0 / sqrt((double)N / (double)NGRAPH));
    readout<<<(N + 63) / 64, 256, 0, stream>>>(
        s_buf, nattr, Wread, batch, (float*)d_out, N, pool_scale);
}

// Round 7
// 597.214 us; speedup vs baseline: 1.3022x; 1.0582x over previous
//
#include <hip/hip_runtime.h>
#include <math.h>

#define MUL 32
#define NATTR 4
#define NBASIS 10
#define HID 64
#define OUT_DIM 16
#define NGRAPH 8

#define PI_F 3.14159265358979323846f
#define SQRT3_F 1.7320508075688772f
#define INV_SQRT3_F 0.5773502691896258f
#define INV_SQRT10_F 0.31622776601683794f
#define INV_SQRTNN_F 0.17677669529663687f   // 1/sqrt(32)
#define NORM128_F 0.08838834764831845f      // 1/sqrt(128)
#define NORM256_F 0.0625f                   // 1/sqrt(256)
#define C_S_F 0.3826834323650898f           // sin(pi/8)
#define C_X_F 0.9238795325112867f           // cos(pi/8)
#define CSTEP_F (4.0f/9.0f)                 // linspace(0,4,10) step

#define HT_STRIDE 132                        // 128 + 4 pad; 132*4B = 16B-aligned rows

// ---------------------------------------------------------------- init s,v
__global__ void init_sv(const float* __restrict__ x,
                        float* __restrict__ s, float* __restrict__ v, int N) {
    int i = blockIdx.x * 256 + threadIdx.x;
    if (i >= N * 128) return;
    int n = i >> 7, c = i & 127;
    float val = x[i];
    if (c < 32) s[n * 32 + c] = val;
    else        v[n * 96 + (c - 32)] = val;
}

// ---------------------------------------------------------------- CSR build
__global__ void csr_count(const int* __restrict__ edst, int* __restrict__ cnt, int E) {
    int e = blockIdx.x * 256 + threadIdx.x;
    if (e < E) atomicAdd(&cnt[edst[e]], 1);
}

__global__ void csr_scan(const int* __restrict__ cnt, int* __restrict__ off,
                         int* __restrict__ cursor, int N) {
    __shared__ int sums[256];
    int t = threadIdx.x;
    int chunk = (N + 255) / 256;
    int lo = t * chunk, hi = lo + chunk; if (hi > N) hi = N;
    int s = 0;
    for (int i = lo; i < hi; i++) s += cnt[i];
    sums[t] = s;
    __syncthreads();
    for (int d = 1; d < 256; d <<= 1) {
        int v = (t >= d) ? sums[t - d] : 0;
        __syncthreads();
        sums[t] += v;
        __syncthreads();
    }
    int run = (t == 0) ? 0 : sums[t - 1];
    for (int i = lo; i < hi; i++) {
        off[i] = run; cursor[i] = run;
        run += cnt[i];
    }
}

// fill: scatter edge_vec + src into CSR slot order; src rides in .w as int bits.
__global__ void csr_fill(const int* __restrict__ edst, const int* __restrict__ esrc,
                         const float* __restrict__ edge_vec,
                         int* __restrict__ cursor,
                         float* __restrict__ vec_csr, int E) {
    int e = blockIdx.x * 256 + threadIdx.x;
    if (e < E) {
        int p = atomicAdd(&cursor[edst[e]], 1);
        float4 vv = {edge_vec[e * 3 + 0], edge_vec[e * 3 + 1], edge_vec[e * 3 + 2],
                     __int_as_float(esrc[e])};
        *(float4*)(vec_csr + (size_t)p * 4) = vv;
    }
}

// ------------------------------------------- node fctp, scalar path
// out0 = sc_s [n*32+w]; xs goes into xsv[n*128 + w*4 + 3].
__global__ __launch_bounds__(256, 2) void node_s_fctp(
    const float* __restrict__ s, const float* __restrict__ attr,
    const float* __restrict__ W0, const float* __restrict__ W1,
    float* __restrict__ out0, float* __restrict__ xsv, int N) {
    __shared__ float w0[4096], w1[4096];
    __shared__ float sh_s[8][32];
    int ln = threadIdx.x >> 5, w = threadIdx.x & 31;
    for (int i = threadIdx.x; i < 4096; i += 256) { w0[i] = W0[i]; w1[i] = W1[i]; }
    for (int g = 0; g < 4; g++) {
        int n = blockIdx.x * 32 + g * 8 + ln;
        bool valid = n < N;
        __syncthreads();
        if (valid) sh_s[ln][w] = s[n * 32 + w];
        __syncthreads();
        if (!valid) continue;
        float4 at = *(const float4*)(attr + n * 4);
        float fa[4] = {at.x, at.y, at.z, at.w};
        float acc0 = 0.f, acc1 = 0.f;
        for (int u = 0; u < 32; u++) {
            float su = sh_s[ln][u];
            int base = u * 128 + w;
#pragma unroll
            for (int a = 0; a < 4; a++) {
                float c = su * fa[a];
                acc0 += c * w0[base + a * 32];
                acc1 += c * w1[base + a * 32];
            }
        }
        out0[n * 32 + w] = acc0 * NORM128_F;
        xsv[(size_t)n * 128 + w * 4 + 3] = acc1 * NORM128_F;
    }
}

// ------------------------------------------- node fctp, vector path
// out0 = sc_v [n*96+..]; xv goes into xsv[n*128 + w*4 + {0,1,2}].
__global__ __launch_bounds__(256, 2) void node_v_fctp(
    const float* __restrict__ v, const float* __restrict__ attr,
    const float* __restrict__ W0, const float* __restrict__ W1,
    float* __restrict__ out0, float* __restrict__ xsv, int N) {
    __shared__ float w0[4096], w1[4096];
    __shared__ float sh_v[8][96];
    int ln = threadIdx.x >> 5, w = threadIdx.x & 31;
    for (int i = threadIdx.x; i < 4096; i += 256) { w0[i] = W0[i]; w1[i] = W1[i]; }
    for (int g = 0; g < 4; g++) {
        int n = blockIdx.x * 32 + g * 8 + ln;
        bool valid = n < N;
        __syncthreads();
        if (valid) {
            sh_v[ln][w * 3 + 0] = v[n * 96 + w * 3 + 0];
            sh_v[ln][w * 3 + 1] = v[n * 96 + w * 3 + 1];
            sh_v[ln][w * 3 + 2] = v[n * 96 + w * 3 + 2];
        }
        __syncthreads();
        if (!valid) continue;
        float4 at = *(const float4*)(attr + n * 4);
        float fa[4] = {at.x, at.y, at.z, at.w};
        float a00 = 0, a01 = 0, a02 = 0, a10 = 0, a11 = 0, a12 = 0;
        for (int u = 0; u < 32; u++) {
            float vu0 = sh_v[ln][u * 3 + 0];
            float vu1 = sh_v[ln][u * 3 + 1];
            float vu2 = sh_v[ln][u * 3 + 2];
            int base = u * 128 + w;
#pragma unroll
            for (int a = 0; a < 4; a++) {
                float f = fa[a];
                float c0 = vu0 * f, c1 = vu1 * f, c2 = vu2 * f;
                float W0v = w0[base + a * 32], W1v = w1[base + a * 32];
                a00 += c0 * W0v; a01 += c1 * W0v; a02 += c2 * W0v;
                a10 += c0 * W1v; a11 += c1 * W1v; a12 += c2 * W1v;
            }
        }
        out0[n * 96 + w * 3 + 0] = a00 * NORM128_F;
        out0[n * 96 + w * 3 + 1] = a01 * NORM128_F;
        out0[n * 96 + w * 3 + 2] = a02 * NORM128_F;
        float* xp = xsv + (size_t)n * 128 + w * 4;
        xp[0] = a10 * NORM128_F;
        xp[1] = a11 * NORM128_F;
        xp[2] = a12 * NORM128_F;
    }
}

// ---------------------------------------------------------------- edge weights
// 128 CSR slots/block. Phase 1: emb -> h (silu), stored k-major hT[64][132].
// Phase 2: 8 edges x 8 outs per thread, ds_read_b128 broadcasts, 64 FMA/k.
__global__ __launch_bounds__(256, 2) void edge_weights(
    const float* __restrict__ vec_csr,
    const float* __restrict__ Wfc1, const float* __restrict__ Wfc2,
    float* __restrict__ w_buf, float* __restrict__ y_buf, int E) {
    __shared__ float sh_wfc1[NBASIS * 64];          // [j][k]
    __shared__ float sh_embT[NBASIS * 128];         // [j][e]
    __shared__ __align__(16) float sh_hT[64 * HT_STRIDE];  // [k][e]

    int tid = threadIdx.x;
    int e0 = blockIdx.x * 128;

    for (int i = tid; i < 640; i += 256) sh_wfc1[i] = Wfc1[i];
    if (tid < 128) {
        int e = e0 + tid;
        float ex = 0.f, ey = 0.f, ez = 0.f, srcbits = 0.f;
        if (e < E) {
            float4 vv = *(const float4*)(vec_csr + (size_t)e * 4);
            ex = vv.x; ey = vv.y; ez = vv.z; srcbits = vv.w;
        }
        float len = sqrtf(ex * ex + ey * ey + ez * ez);
        float rinv = SQRT3_F / (len + 1e-9f);
        if (e < E) {
            float4 y4 = {ex * rinv, ey * rinv, ez * rinv, srcbits};
            *(float4*)(y_buf + (size_t)e * 4) = y4;
        }
        float uu = 2.0f * (len * 0.25f - 1.0f);
        float cut = (uu > 0.0f) ? 0.0f
                  : ((uu < -1.0f) ? 1.0f : 0.5f * (1.0f - __cosf(PI_F * uu)));
#pragma unroll
        for (int j = 0; j < NBASIS; j++) {
            float d = (len - j * CSTEP_F) * 2.5f;
            sh_embT[j * 128 + tid] = __expf(-d * d) * cut;
        }
    }
    __syncthreads();

    // ---- phase 1 (e-major): thread (e = tid&127, kg = tid>>7) computes
    // h[k][e] for k = kg*32..kg*32+31. All LDS writes stride-1: conflict-free.
    {
        int e = tid & 127;
        int kg = tid >> 7;
        float emb[NBASIS];
#pragma unroll
        for (int j = 0; j < NBASIS; j++) emb[j] = sh_embT[j * 128 + e];
        float acc[32];
#pragma unroll
        for (int i = 0; i < 32; i++) acc[i] = 0.f;
#pragma unroll
        for (int j = 0; j < NBASIS; j++) {
            float ej = emb[j];
            const float* wrow = sh_wfc1 + j * 64 + kg * 32;
#pragma unroll
            for (int i = 0; i < 32; i++) acc[i] += ej * wrow[i];
        }
#pragma unroll
        for (int i = 0; i < 32; i++) {
            float a = acc[i] * INV_SQRT10_F;
            sh_hT[(kg * 32 + i) * HT_STRIDE + e] = a / (1.0f + __expf(-a));
        }
    }
    __syncthreads();

    // ---- phase 2: w[e][wq] = (h @ Wfc2)/8 ; tile 8 edges x 8 outputs.
    {
        int wt = tid & 15;   // outputs wt*8 .. wt*8+7
        int et = tid >> 4;   // edges  et*8 .. et*8+7
        float acc[8][8];
#pragma unroll
        for (int ie = 0; ie < 8; ie++)
#pragma unroll
            for (int j = 0; j < 8; j++) acc[ie][j] = 0.f;
        const float* W2 = Wfc2 + wt * 8;
        const float* hbase = sh_hT + et * 8;
        for (int k = 0; k < HID; k++) {
            float4 b0 = *(const float4*)(W2 + k * 128);
            float4 b1 = *(const float4*)(W2 + k * 128 + 4);
            float bv[8] = {b0.x, b0.y, b0.z, b0.w, b1.x, b1.y, b1.z, b1.w};
            float4 h0 = *(const float4*)(hbase + k * HT_STRIDE);
            float4 h1 = *(const float4*)(hbase + k * HT_STRIDE + 4);
            float hv[8] = {h0.x, h0.y, h0.z, h0.w, h1.x, h1.y, h1.z, h1.w};
#pragma unroll
            for (int ie = 0; ie < 8; ie++)
#pragma unroll
                for (int j = 0; j < 8; j++) acc[ie][j] += hv[ie] * bv[j];
        }
#pragma unroll
        for (int ie = 0; ie < 8; ie++) {
            int e = e0 + et * 8 + ie;
            if (e >= E) continue;
            float4 lo = {acc[ie][0] * 0.125f, acc[ie][1] * 0.125f,
                         acc[ie][2] * 0.125f, acc[ie][3] * 0.125f};
            float4 hi = {acc[ie][4] * 0.125f, acc[ie][5] * 0.125f,
                         acc[ie][6] * 0.125f, acc[ie][7] * 0.125f};
            float* dst = w_buf + (size_t)e * 128 + wt * 8;
            *(float4*)(dst)     = lo;
            *(float4*)(dst + 4) = hi;
        }
    }
}

// ---------------------------------------------------------------- gather
// one wave per dst node; half-wave per edge-slot; lane u = channel u.
// 6 VMEM/iter: y(float4 bcast, carries src), xsv(float4), 4 w dwords.
__global__ __launch_bounds__(256, 4) void gather_msgs(
    const int* __restrict__ off, const int* __restrict__ cnt,
    const float* __restrict__ w_buf, const float* __restrict__ y_buf,
    const float* __restrict__ xsv,
    float* __restrict__ agg_s, float* __restrict__ agg_v, int N) {
    int node = blockIdx.x * 4 + (threadIdx.x >> 6);
    if (node >= N) return;
    int lane = threadIdx.x & 63;
    int half = lane >> 5;
    int u = lane & 31;
    int o = off[node], deg = cnt[node];
    float as0 = 0, as1 = 0;
    float av00 = 0, av01 = 0, av02 = 0, av10 = 0, av11 = 0, av12 = 0;

    auto body = [&](int slot) {
        size_t p = (size_t)slot;
        float4 y = *(const float4*)(y_buf + p * 4);
        int src = __float_as_int(y.w);
        float4 x4 = *(const float4*)(xsv + (size_t)src * 128 + u * 4);
        const float* wp = w_buf + p * 128 + u;
        float wa = wp[0], wb = wp[32], wc = wp[64], wd = wp[96];
        as0 += wa * x4.w;
        as1 += wb * (y.x * x4.x + y.y * x4.y + y.z * x4.z) * INV_SQRT3_F;
        float t = wc * x4.w;
        av00 += t * y.x;  av01 += t * y.y;  av02 += t * y.z;
        av10 += wd * x4.x; av11 += wd * x4.y; av12 += wd * x4.z;
    };

    int i = half;
    for (; i + 2 < deg; i += 4) { body(o + i); body(o + i + 2); }
    for (; i < deg; i += 2) body(o + i);

    as0 += __shfl_down(as0, 32);  as1 += __shfl_down(as1, 32);
    av00 += __shfl_down(av00, 32); av01 += __shfl_down(av01, 32); av02 += __shfl_down(av02, 32);
    av10 += __shfl_down(av10, 32); av11 += __shfl_down(av11, 32); av12 += __shfl_down(av12, 32);
    if (half == 0) {
        agg_s[node * 64 + u]      = as0 * INV_SQRTNN_F;
        agg_s[node * 64 + 32 + u] = as1 * INV_SQRTNN_F;
        float* av = agg_v + (size_t)node * 192;
        av[u * 3 + 0]      = av00 * INV_SQRTNN_F;
        av[u * 3 + 1]      = av01 * INV_SQRTNN_F;
        av[u * 3 + 2]      = av02 * INV_SQRTNN_F;
        av[96 + u * 3 + 0] = av10 * INV_SQRTNN_F;
        av[96 + u * 3 + 1] = av11 * INV_SQRTNN_F;
        av[96 + u * 3 + 2] = av12 * INV_SQRTNN_F;
    }
}

// ------------------------------------------- second fctp (64-wide) + s update
__global__ __launch_bounds__(256, 2) void node_update_s(
    const float* __restrict__ agg_s, const float* __restrict__ attr,
    const float* __restrict__ W0, const float* __restrict__ sc_s,
    float* __restrict__ s, float* __restrict__ snew, int N) {
    __shared__ float w0[8192];
    __shared__ float sh_as[8][64];
    int ln = threadIdx.x >> 5, w = threadIdx.x & 31;
    for (int i = threadIdx.x; i < 8192; i += 256) w0[i] = W0[i];
    for (int g = 0; g < 4; g++) {
        int n = blockIdx.x * 32 + g * 8 + ln;
        bool valid = n < N;
        __syncthreads();
        if (valid) {
            sh_as[ln][w] = agg_s[n * 64 + w];
            sh_as[ln][32 + w] = agg_s[n * 64 + 32 + w];
        }
        __syncthreads();
        if (!valid) continue;
        float4 at = *(const float4*)(attr + n * 4);
        float fa[4] = {at.x, at.y, at.z, at.w};
        float acc = 0.f;
        for (int u = 0; u < 64; u++) {
            float g_ = sh_as[ln][u];
            int base = u * 128 + w;
#pragma unroll
            for (int a = 0; a < 4; a++) acc += g_ * fa[a] * w0[base + a * 32];
        }
        float os = acc * NORM256_F;
        float sn = C_S_F * sc_s[n * 32 + w] + C_X_F * os;
        snew[n * 32 + w] = sn;
        float sig = 1.0f / (1.0f + __expf(-sn));
        s[n * 32 + w] += sn * sig;   // silu(sn)
    }
}

// ------------------------------------------- second fctp (64-wide) + v update
__global__ __launch_bounds__(256, 2) void node_update_v(
    const float* __restrict__ agg_v, const float* __restrict__ attr,
    const float* __restrict__ W1, const float* __restrict__ sc_v,
    const float* __restrict__ snew, float* __restrict__ v, int N) {
    __shared__ float w1[8192];
    __shared__ float sh_av[8][192];
    int ln = threadIdx.x >> 5, w = threadIdx.x & 31;
    for (int i = threadIdx.x; i < 8192; i += 256) w1[i] = W1[i];
    for (int g = 0; g < 4; g++) {
        int n = blockIdx.x * 32 + g * 8 + ln;
        bool valid = n < N;
        __syncthreads();
        if (valid) {
#pragma unroll
            for (int i = 0; i < 6; i++)
                sh_av[ln][w * 6 + i] = agg_v[(size_t)n * 192 + w * 6 + i];
        }
        __syncthreads();
        if (!valid) continue;
        float4 at = *(const float4*)(attr + n * 4);
        float fa[4] = {at.x, at.y, at.z, at.w};
        float a0 = 0.f, a1 = 0.f, a2 = 0.f;
        for (int u = 0; u < 64; u++) {
            float g0 = sh_av[ln][u * 3 + 0];
            float g1 = sh_av[ln][u * 3 + 1];
            float g2 = sh_av[ln][u * 3 + 2];
            int base = u * 128 + w;
#pragma unroll
            for (int a = 0; a < 4; a++) {
                float f = fa[a];
                float W1v = w1[base + a * 32];
                a0 += g0 * f * W1v; a1 += g1 * f * W1v; a2 += g2 * f * W1v;
            }
        }
        float sn = snew[n * 32 + w];
        float sig = 1.0f / (1.0f + __expf(-sn));
        float ov0 = a0 * NORM256_F, ov1 = a1 * NORM256_F, ov2 = a2 * NORM256_F;
        v[n * 96 + w * 3 + 0] += (C_S_F * sc_v[n * 96 + w * 3 + 0] + C_X_F * ov0) * sig;
        v[n * 96 + w * 3 + 1] += (C_S_F * sc_v[n * 96 + w * 3 + 1] + C_X_F * ov1) * sig;
        v[n * 96 + w * 3 + 2] += (C_S_F * sc_v[n * 96 + w * 3 + 2] + C_X_F * ov2) * sig;
    }
}

// ---------------------------------------------------------------- readout
__global__ __launch_bounds__(256) void readout(
    const float* __restrict__ s, const float* __restrict__ attr,
    const float* __restrict__ Wread, const int* __restrict__ batch,
    float* __restrict__ out, int N, float pool_scale) {
    __shared__ float wr[2048];
    __shared__ float red[NGRAPH * 16];
    for (int i = threadIdx.x; i < 2048; i += 256) wr[i] = Wread[i];
    if (threadIdx.x < NGRAPH * 16) red[threadIdx.x] = 0.f;
    __syncthreads();
    int ln = threadIdx.x >> 4, w = threadIdx.x & 15;
    for (int g = 0; g < 4; g++) {
        int n = blockIdx.x * 64 + g * 16 + ln;
        if (n < N) {
            float4 at = *(const float4*)(attr + n * 4);
            float fa[4] = {at.x, at.y, at.z, at.w};
            float acc = 0.f;
            for (int u = 0; u < 32; u++) {
                float su = s[n * 32 + u];
                int base = u * 64 + w;
#pragma unroll
                for (int a = 0; a < 4; a++) acc += su * fa[a] * wr[base + a * 16];
            }
            atomicAdd(&red[batch[n] * 16 + w], acc);
        }
    }
    __syncthreads();
    if (threadIdx.x < NGRAPH * 16) {
        float val = red[threadIdx.x];
        if (val != 0.f)
            atomicAdd(&out[threadIdx.x], val * NORM128_F * pool_scale);
    }
}

// ---------------------------------------------------------------- launch
extern "C" void kernel_launch(void* const* d_in, const int* in_sizes, int n_in,
                              void* d_out, int out_size, void* d_ws, size_t ws_size,
                              hipStream_t stream) {
    const float* x        = (const float*)d_in[0];
    const float* nattr    = (const float*)d_in[1];
    const float* edge_vec = (const float*)d_in[2];
    const int*   batch    = (const int*)d_in[3];
    const int*   esrc     = (const int*)d_in[4];
    const int*   edst     = (const int*)d_in[5];
    const float* Wsc0  = (const float*)d_in[6];
    const float* Wsc1  = (const float*)d_in[7];
    const float* Wl10  = (const float*)d_in[8];
    const float* Wl11  = (const float*)d_in[9];
    const float* Wfc1  = (const float*)d_in[10];
    const float* Wfc2  = (const float*)d_in[11];
    const float* Wl20  = (const float*)d_in[12];
    const float* Wl21  = (const float*)d_in[13];
    const float* Wread = (const float*)d_in[14];

    int N = in_sizes[0] / (MUL * 4);
    int E = in_sizes[2] / 3;

    float* p = (float*)d_ws;
    float* w_buf   = p; p += (size_t)E * 128;   // CSR-slot indexed [p][wq]
    float* y_buf   = p; p += (size_t)E * 4;     // {ux,uy,uz,src-bits}
    float* vec_csr = p; p += (size_t)E * 4;     // {ex,ey,ez,src-bits}
    float* s_buf  = p; p += (size_t)N * 32;
    float* v_buf  = p; p += (size_t)N * 96;
    float* sc_s   = p; p += (size_t)N * 32;
    float* sc_v   = p; p += (size_t)N * 96;
    float* xsv    = p; p += (size_t)N * 128;    // {xv0,xv1,xv2,xs} per (n,u)
    float* snew   = p; p += (size_t)N * 32;
    float* agg_s  = p; p += (size_t)N * 64;
    float* agg_v  = p; p += (size_t)N * 192;
    int* cnt     = (int*)p; p += N;
    int* off     = (int*)p; p += N;
    int* cursor  = (int*)p; p += N;

    init_sv<<<(N * 128 + 255) / 256, 256, 0, stream>>>(x, s_buf, v_buf, N);
    hipMemsetAsync(d_out, 0, (size_t)out_size * sizeof(float), stream);

    // CSR by destination; edge data scattered into CSR order once.
    hipMemsetAsync(cnt, 0, (size_t)N * sizeof(int), stream);
    csr_count<<<(E + 255) / 256, 256, 0, stream>>>(edst, cnt, E);
    csr_scan<<<1, 256, 0, stream>>>(cnt, off, cursor, N);
    csr_fill<<<(E + 255) / 256, 256, 0, stream>>>(
        edst, esrc, edge_vec, cursor, vec_csr, E);

    for (int l = 0; l < 2; l++) {
        node_s_fctp<<<(N + 31) / 32, 256, 0, stream>>>(
            s_buf, nattr, Wsc0 + l * 4096, Wl10 + l * 4096, sc_s, xsv, N);
        node_v_fctp<<<(N + 31) / 32, 256, 0, stream>>>(
            v_buf, nattr, Wsc1 + l * 4096, Wl11 + l * 4096, sc_v, xsv, N);
        edge_weights<<<(E + 127) / 128, 256, 0, stream>>>(
            vec_csr, Wfc1 + l * 640, Wfc2 + l * 8192, w_buf, y_buf, E);
        gather_msgs<<<(N + 3) / 4, 256, 0, stream>>>(
            off, cnt, w_buf, y_buf, xsv, agg_s, agg_v, N);
        node_update_s<<<(N + 31) / 32, 256, 0, stream>>>(
            agg_s, nattr, Wl20 + l * 8192, sc_s, s_buf, snew, N);
        node_update_v<<<(N + 31) / 32, 256, 0, stream>>>(
            agg_v, nattr, Wl21 + l * 8192, sc_v, snew, v_buf, N);
    }

    float pool_scale = (float)(1.0 / sqrt((double)N / (double)NGRAPH));
    readout<<<(N + 63) / 64, 256, 0, stream>>>(
        s_buf, nattr, Wread, batch, (float*)d_out, N, pool_scale);
}